// Round 1
// baseline (437.841 us; speedup 1.0000x reference)
//
#include <hip/hip_runtime.h>
#include <hip/hip_bf16.h>
#include <stdint.h>

// Problem constants
#define BATCH 2
#define NPTS 4096
#define DMODEL 1024
#define NHEAD 16
#define HDIM 64
#define KNN 16
#define MASKN 131072   // 32*64*64

typedef __attribute__((ext_vector_type(8))) short bf16x8;
typedef __attribute__((ext_vector_type(4))) float f32x4;

__device__ __forceinline__ float b2f(unsigned short u) {
    union { unsigned int i; float f; } c; c.i = ((unsigned int)u) << 16; return c.f;
}
__device__ __forceinline__ unsigned short f2b(float f) {
    unsigned int x = __float_as_uint(f);
    unsigned int r = (x + 0x7fffu + ((x >> 16) & 1u)) >> 16;
    return (unsigned short)r;
}
__device__ __forceinline__ unsigned int pack2f(float a, float b) {
    return (unsigned int)f2b(a) | ((unsigned int)f2b(b) << 16);
}

// ---------------------------------------------------------------------------
// 1) Extract active indices from mask (handles bool-byte or int32 storage)
// ---------------------------------------------------------------------------
__global__ __launch_bounds__(1024) void extract_active(const unsigned char* __restrict__ m8,
                                                       int* __restrict__ act) {
    __shared__ int sc[1024];
    __shared__ int s_total;
    const int t = threadIdx.x;
    const int chunk = MASKN / 1024;  // 128
    int cnt = 0;
    for (int i = 0; i < chunk; ++i) cnt += (m8[t * chunk + i] != 0) ? 1 : 0;
    sc[t] = cnt; __syncthreads();
    for (int off = 1; off < 1024; off <<= 1) {
        int v = (t >= off) ? sc[t - off] : 0;
        __syncthreads();
        sc[t] += v;
        __syncthreads();
    }
    if (t == 1023) s_total = sc[1023];
    __syncthreads();
    if (s_total == NPTS) {
        // bool stored as 1 byte per element
        int pos = sc[t] - cnt;
        for (int i = 0; i < chunk; ++i) {
            int g = t * chunk + i;
            if (m8[g]) act[pos++] = g;
        }
    } else {
        // stored as int32
        const int* m32 = (const int*)m8;
        int cnt2 = 0;
        for (int i = 0; i < chunk; ++i) cnt2 += (m32[t * chunk + i] != 0) ? 1 : 0;
        __syncthreads();
        sc[t] = cnt2; __syncthreads();
        for (int off = 1; off < 1024; off <<= 1) {
            int v = (t >= off) ? sc[t - off] : 0;
            __syncthreads();
            sc[t] += v;
            __syncthreads();
        }
        int pos = sc[t] - cnt2;
        for (int i = 0; i < chunk; ++i) {
            int g = t * chunk + i;
            if (m32[g]) act[pos++] = g;
        }
    }
}

// ---------------------------------------------------------------------------
// 2) kNN: for each active point, 16 nearest neighbors (excluding self).
//    packed = (d2<<12)|j reproduces top_k's (value, index) stable ordering.
//    4 threads per query, each scans a stride-4 subset, merge via LDS.
// ---------------------------------------------------------------------------
__global__ __launch_bounds__(256) void knn_kernel(const int* __restrict__ act,
                                                  int* __restrict__ nbr) {
    __shared__ int act_s[NPTS];
    __shared__ int mbuf[64][4][17];
    const int t = threadIdx.x;
    for (int i = t; i < NPTS; i += 256) act_s[i] = act[i];
    __syncthreads();
    const int q = blockIdx.x * 64 + (t >> 2);
    const int sub = t & 3;
    const int aq = act_s[q];
    const int qz = aq >> 12, qy = (aq >> 6) & 63, qx = aq & 63;
    int best[17];
    #pragma unroll
    for (int i = 0; i < 17; ++i) best[i] = 0x7FFFFFFF;
    for (int j = sub; j < NPTS; j += 4) {
        const int aj = act_s[j];
        const int dz = (aj >> 12) - qz;
        const int dy = ((aj >> 6) & 63) - qy;
        const int dx = (aj & 63) - qx;
        const int d2 = dz * dz + dy * dy + dx * dx;
        int p = (d2 << 12) | j;
        if (p < best[16]) {
            #pragma unroll
            for (int u = 0; u < 17; ++u) {
                const bool lt = p < best[u];
                const int tmp = best[u];
                best[u] = lt ? p : best[u];
                p = lt ? tmp : p;
            }
        }
    }
    #pragma unroll
    for (int i = 0; i < 17; ++i) mbuf[t >> 2][sub][i] = best[i];
    __syncthreads();
    if (sub == 0) {
        for (int s = 1; s < 4; ++s) {
            for (int i = 0; i < 17; ++i) {
                int p = mbuf[t >> 2][s][i];
                if (p < best[16]) {
                    #pragma unroll
                    for (int u = 0; u < 17; ++u) {
                        const bool lt = p < best[u];
                        const int tmp = best[u];
                        best[u] = lt ? p : best[u];
                        p = lt ? tmp : p;
                    }
                }
            }
        }
        #pragma unroll
        for (int kk = 0; kk < KNN; ++kk) nbr[q * KNN + kk] = best[kk + 1] & 4095;
    }
}

// ---------------------------------------------------------------------------
// 3) QKV GEMM: C[m][n] = sum_k X[m][k] * W[n][k]  (X: 8192x1024 f32,
//    W: 1024x1024 f32, C bf16). 128x128 tile, 4 waves, mfma 16x16x32 bf16.
//    Staging converts f32->bf16 in-flight (saves ws and a cast pass).
// ---------------------------------------------------------------------------
__device__ __forceinline__ void stage16(unsigned short* dst, const float* src) {
    const float4 a = ((const float4*)src)[0];
    const float4 b = ((const float4*)src)[1];
    const float4 c = ((const float4*)src)[2];
    const float4 d = ((const float4*)src)[3];
    uint4 w0, w1;
    w0.x = pack2f(a.x, a.y); w0.y = pack2f(a.z, a.w);
    w0.z = pack2f(b.x, b.y); w0.w = pack2f(b.z, b.w);
    w1.x = pack2f(c.x, c.y); w1.y = pack2f(c.z, c.w);
    w1.z = pack2f(d.x, d.y); w1.w = pack2f(d.z, d.w);
    ((uint4*)dst)[0] = w0;
    ((uint4*)dst)[1] = w1;
}

__global__ __launch_bounds__(256) void gemm_qkv(
    const float* __restrict__ X,
    const float* __restrict__ W0, const float* __restrict__ W1, const float* __restrict__ W2,
    unsigned short* __restrict__ O0, unsigned short* __restrict__ O1, unsigned short* __restrict__ O2)
{
    const int K = DMODEL, N = DMODEL;
    const float* W = (blockIdx.z == 0) ? W0 : (blockIdx.z == 1) ? W1 : W2;
    unsigned short* C = (blockIdx.z == 0) ? O0 : (blockIdx.z == 1) ? O1 : O2;
    __shared__ unsigned short As[128 * 32];
    __shared__ unsigned short Bs[128 * 32];
    const int tid = threadIdx.x;
    const int rowBase = blockIdx.x * 128;
    const int colBase = blockIdx.y * 128;
    const int lane = tid & 63, w = tid >> 6;
    const int wr = w >> 1, wc = w & 1;
    const int lr = lane & 15, kg = lane >> 4;
    const int srow = tid >> 1;
    const int scol = (tid & 1) * 16;

    f32x4 acc[4][4];
    const f32x4 zero = {0.f, 0.f, 0.f, 0.f};
    #pragma unroll
    for (int i = 0; i < 4; ++i)
        #pragma unroll
        for (int j = 0; j < 4; ++j) acc[i][j] = zero;

    const float* Arow = &X[(size_t)(rowBase + srow) * K + scol];
    const float* Brow = &W[(size_t)(colBase + srow) * K + scol];
    unsigned short* Adst = &As[srow * 32 + scol];
    unsigned short* Bdst = &Bs[srow * 32 + scol];

    for (int kb = 0; kb < K; kb += 32) {
        __syncthreads();
        stage16(Adst, Arow + kb);
        stage16(Bdst, Brow + kb);
        __syncthreads();
        bf16x8 af[4], bfr[4];
        #pragma unroll
        for (int mi = 0; mi < 4; ++mi)
            af[mi] = *(const bf16x8*)&As[(wr * 64 + mi * 16 + lr) * 32 + kg * 8];
        #pragma unroll
        for (int ni = 0; ni < 4; ++ni)
            bfr[ni] = *(const bf16x8*)&Bs[(wc * 64 + ni * 16 + lr) * 32 + kg * 8];
        #pragma unroll
        for (int mi = 0; mi < 4; ++mi)
            #pragma unroll
            for (int ni = 0; ni < 4; ++ni)
                acc[mi][ni] = __builtin_amdgcn_mfma_f32_16x16x32_bf16(af[mi], bfr[ni], acc[mi][ni], 0, 0, 0);
    }
    // Epilogue: D row = (lane>>4)*4 + j, col = lane&15  [verified m89/m91]
    #pragma unroll
    for (int mi = 0; mi < 4; ++mi)
        #pragma unroll
        for (int ni = 0; ni < 4; ++ni) {
            const int row0 = rowBase + wr * 64 + mi * 16 + kg * 4;
            const int col = colBase + wc * 64 + ni * 16 + lr;
            #pragma unroll
            for (int j = 0; j < 4; ++j)
                C[(size_t)(row0 + j) * N + col] = f2b(acc[mi][ni][j]);
        }
}

// ---------------------------------------------------------------------------
// 4) Attention: one block per (b,n). Stage q + 16 neighbor k/v rows in LDS,
//    thread (h,kk) computes a score, 16-lane shuffle softmax, then PV.
// ---------------------------------------------------------------------------
__global__ __launch_bounds__(256) void attn_kernel(
    const unsigned short* __restrict__ Q, const unsigned short* __restrict__ Kb,
    const unsigned short* __restrict__ Vb, const int* __restrict__ nbr,
    float* __restrict__ out)
{
    const int n = blockIdx.x;
    const int b = blockIdx.y;
    __shared__ unsigned short q_s[DMODEL];
    __shared__ unsigned short k_s[KNN][1028];   // pad -> ~4-way instead of 16-way
    __shared__ unsigned short v_s[KNN][DMODEL];
    __shared__ float a_s[NHEAD][KNN];
    __shared__ int nb_s[KNN];
    const int tid = threadIdx.x;
    if (tid < KNN) nb_s[tid] = nbr[n * KNN + tid];
    *(int2*)&q_s[tid * 4] = *(const int2*)&Q[((size_t)b * NPTS + n) * DMODEL + tid * 4];
    __syncthreads();
    #pragma unroll
    for (int kk = 0; kk < KNN; ++kk) {
        const int j = nb_s[kk];
        const size_t base = ((size_t)b * NPTS + j) * DMODEL;
        *(int2*)&k_s[kk][tid * 4] = *(const int2*)&Kb[base + tid * 4];
        *(int2*)&v_s[kk][tid * 4] = *(const int2*)&Vb[base + tid * 4];
    }
    __syncthreads();
    const int h = tid >> 4, kk = tid & 15;
    const unsigned short* qp = &q_s[h * HDIM];
    const unsigned short* kp = &k_s[kk][h * HDIM];
    float s = 0.f;
    #pragma unroll
    for (int d = 0; d < HDIM; ++d) s += b2f(qp[d]) * b2f(kp[d]);
    s *= 0.125f;  // 1/sqrt(64)
    float m = s;
    #pragma unroll
    for (int off = 8; off >= 1; off >>= 1) m = fmaxf(m, __shfl_xor(m, off, 16));
    const float e = __expf(s - m);
    float sum = e;
    #pragma unroll
    for (int off = 8; off >= 1; off >>= 1) sum += __shfl_xor(sum, off, 16);
    a_s[h][kk] = e / sum;
    __syncthreads();
    const size_t obase = ((size_t)b * NPTS + n) * DMODEL;
    #pragma unroll
    for (int r = 0; r < 4; ++r) {
        const int o = tid + 256 * r;
        const int h2 = o >> 6;
        float accv = 0.f;
        #pragma unroll
        for (int k2 = 0; k2 < KNN; ++k2) accv += a_s[h2][k2] * b2f(v_s[k2][o]);
        out[obase + o] = accv;
    }
}

// ---------------------------------------------------------------------------
// 5) metric = k.mean(axis=H): out2[b,n,d] = (1/16) sum_h k[b,n,h*64+d]
// ---------------------------------------------------------------------------
__global__ __launch_bounds__(256) void metric_kernel(const unsigned short* __restrict__ Kb,
                                                     float* __restrict__ mout) {
    const int i = blockIdx.x * 256 + threadIdx.x;
    if (i >= BATCH * NPTS * HDIM) return;
    const int d = i & 63;
    const int bn = i >> 6;
    const unsigned short* kp = &Kb[(size_t)bn * DMODEL + d];
    float s = 0.f;
    #pragma unroll
    for (int hh = 0; hh < NHEAD; ++hh) s += b2f(kp[hh * HDIM]);
    mout[i] = s * 0.0625f;
}

// ---------------------------------------------------------------------------
extern "C" void kernel_launch(void* const* d_in, const int* in_sizes, int n_in,
                              void* d_out, int out_size, void* d_ws, size_t ws_size,
                              hipStream_t stream) {
    const float* x = (const float*)d_in[0];
    const unsigned char* mask = (const unsigned char*)d_in[1];
    const float* Wq = (const float*)d_in[2];
    const float* Wk = (const float*)d_in[3];
    const float* Wv = (const float*)d_in[4];
    float* out = (float*)d_out;
    char* ws = (char*)d_ws;

    const size_t QKV_BYTES = (size_t)BATCH * NPTS * DMODEL * 2;  // 16 MB each
    unsigned short* qb = (unsigned short*)(ws);
    unsigned short* kb = (unsigned short*)(ws + QKV_BYTES);
    unsigned short* vb = (unsigned short*)(ws + 2 * QKV_BYTES);
    int* act = (int*)(ws + 3 * QKV_BYTES);
    int* nbr = (int*)(ws + 3 * QKV_BYTES + NPTS * sizeof(int));
    if (ws_size < 3 * QKV_BYTES + (size_t)NPTS * sizeof(int) * (1 + KNN)) return;

    extract_active<<<1, 1024, 0, stream>>>(mask, act);
    knn_kernel<<<64, 256, 0, stream>>>(act, nbr);
    gemm_qkv<<<dim3(64, 8, 3), 256, 0, stream>>>(x, Wq, Wk, Wv, qb, kb, vb);
    attn_kernel<<<dim3(NPTS, BATCH), 256, 0, stream>>>(qb, kb, vb, nbr, out);
    metric_kernel<<<(BATCH * NPTS * HDIM + 255) / 256, 256, 0, stream>>>(kb, out + (size_t)BATCH * NPTS * DMODEL);
}

// Round 2
// 336.087 us; speedup vs baseline: 1.3028x; 1.3028x over previous
//
#include <hip/hip_runtime.h>
#include <hip/hip_bf16.h>
#include <stdint.h>

// Problem constants
#define BATCH 2
#define NPTS 4096
#define DMODEL 1024
#define NHEAD 16
#define HDIM 64
#define KNN 16
#define MASKN 131072   // 32*64*64

typedef __attribute__((ext_vector_type(8))) short bf16x8;
typedef __attribute__((ext_vector_type(4))) float f32x4;

__device__ __forceinline__ float b2f(unsigned short u) {
    union { unsigned int i; float f; } c; c.i = ((unsigned int)u) << 16; return c.f;
}
__device__ __forceinline__ unsigned short f2b(float f) {
    unsigned int x = __float_as_uint(f);
    unsigned int r = (x + 0x7fffu + ((x >> 16) & 1u)) >> 16;
    return (unsigned short)r;
}
__device__ __forceinline__ unsigned int pack2f(float a, float b) {
    return (unsigned int)f2b(a) | ((unsigned int)f2b(b) << 16);
}

// ---------------------------------------------------------------------------
// 1) Extract active indices from mask (handles bool-byte or int32 storage)
// ---------------------------------------------------------------------------
__global__ __launch_bounds__(1024) void extract_active(const unsigned char* __restrict__ m8,
                                                       int* __restrict__ act) {
    __shared__ int sc[1024];
    __shared__ int s_total;
    const int t = threadIdx.x;
    const int chunk = MASKN / 1024;  // 128
    int cnt = 0;
    for (int i = 0; i < chunk; ++i) cnt += (m8[t * chunk + i] != 0) ? 1 : 0;
    sc[t] = cnt; __syncthreads();
    for (int off = 1; off < 1024; off <<= 1) {
        int v = (t >= off) ? sc[t - off] : 0;
        __syncthreads();
        sc[t] += v;
        __syncthreads();
    }
    if (t == 1023) s_total = sc[1023];
    __syncthreads();
    if (s_total == NPTS) {
        // bool stored as 1 byte per element
        int pos = sc[t] - cnt;
        for (int i = 0; i < chunk; ++i) {
            int g = t * chunk + i;
            if (m8[g]) act[pos++] = g;
        }
    } else {
        // stored as int32
        const int* m32 = (const int*)m8;
        int cnt2 = 0;
        for (int i = 0; i < chunk; ++i) cnt2 += (m32[t * chunk + i] != 0) ? 1 : 0;
        __syncthreads();
        sc[t] = cnt2; __syncthreads();
        for (int off = 1; off < 1024; off <<= 1) {
            int v = (t >= off) ? sc[t - off] : 0;
            __syncthreads();
            sc[t] += v;
            __syncthreads();
        }
        int pos = sc[t] - cnt2;
        for (int i = 0; i < chunk; ++i) {
            int g = t * chunk + i;
            if (m32[g]) act[pos++] = g;
        }
    }
}

// ---------------------------------------------------------------------------
// 2) kNN: 16 threads per query, 16 queries per block -> 256 blocks (1/CU).
//    Each lane scans a stride-16 subset (256 candidates) keeping a sorted
//    top-17 in registers (compile-time indices only), then a 17-round
//    16-lane shuffle k-way merge. packed = (d2<<12)|j reproduces top_k's
//    (value, index) stable ordering; keys unique -> single winner per round.
// ---------------------------------------------------------------------------
__global__ __launch_bounds__(256) void knn_kernel(const int* __restrict__ act,
                                                  int* __restrict__ nbr) {
    __shared__ int act_s[NPTS];
    const int t = threadIdx.x;
    for (int i = t; i < NPTS; i += 256) act_s[i] = act[i];
    __syncthreads();
    const int q = blockIdx.x * 16 + (t >> 4);
    const int sub = t & 15;
    const int aq = act_s[q];
    const int qz = aq >> 12, qy = (aq >> 6) & 63, qx = aq & 63;
    int best[17];
    #pragma unroll
    for (int i = 0; i < 17; ++i) best[i] = 0x7FFFFFFF;
    for (int j = sub; j < NPTS; j += 16) {
        const int aj = act_s[j];
        const int dz = (aj >> 12) - qz;
        const int dy = ((aj >> 6) & 63) - qy;
        const int dx = (aj & 63) - qx;
        const int d2 = dz * dz + dy * dy + dx * dx;
        int p = (d2 << 12) | j;
        if (p < best[16]) {
            #pragma unroll
            for (int u = 0; u < 17; ++u) {
                const bool lt = p < best[u];
                const int tmp = best[u];
                best[u] = lt ? p : best[u];
                p = lt ? tmp : p;
            }
        }
    }
    // 16-lane k-way merge: 17 rounds of min-extraction.
    int head = best[0];
    int keep = 0;
    #pragma unroll
    for (int r = 0; r < KNN + 1; ++r) {
        int m = head;
        #pragma unroll
        for (int off = 8; off >= 1; off >>= 1) m = min(m, __shfl_xor(m, off, 16));
        if (sub == r - 1) keep = m;          // rank r (1..16) kept by lane r-1
        const bool win = (head == m);        // unique key -> exactly one winner
        #pragma unroll
        for (int u = 0; u < 16; ++u) if (win) best[u] = best[u + 1];
        if (win) best[16] = 0x7FFFFFFF;
        head = best[0];
    }
    nbr[q * KNN + sub] = keep & 4095;        // coalesced 16-wide store
}

// ---------------------------------------------------------------------------
// 3) QKV GEMM: C[m][n] = sum_k X[m][k] * W[n][k]  (X: 8192x1024 f32,
//    W: 1024x1024 f32, C bf16). 128x128 tile, 4 waves, mfma 16x16x32 bf16.
//    Staging converts f32->bf16 in-flight (saves ws and a cast pass).
// ---------------------------------------------------------------------------
__device__ __forceinline__ void stage16(unsigned short* dst, const float* src) {
    const float4 a = ((const float4*)src)[0];
    const float4 b = ((const float4*)src)[1];
    const float4 c = ((const float4*)src)[2];
    const float4 d = ((const float4*)src)[3];
    uint4 w0, w1;
    w0.x = pack2f(a.x, a.y); w0.y = pack2f(a.z, a.w);
    w0.z = pack2f(b.x, b.y); w0.w = pack2f(b.z, b.w);
    w1.x = pack2f(c.x, c.y); w1.y = pack2f(c.z, c.w);
    w1.z = pack2f(d.x, d.y); w1.w = pack2f(d.z, d.w);
    ((uint4*)dst)[0] = w0;
    ((uint4*)dst)[1] = w1;
}

__global__ __launch_bounds__(256) void gemm_qkv(
    const float* __restrict__ X,
    const float* __restrict__ W0, const float* __restrict__ W1, const float* __restrict__ W2,
    unsigned short* __restrict__ O0, unsigned short* __restrict__ O1, unsigned short* __restrict__ O2)
{
    const int K = DMODEL, N = DMODEL;
    const float* W = (blockIdx.z == 0) ? W0 : (blockIdx.z == 1) ? W1 : W2;
    unsigned short* C = (blockIdx.z == 0) ? O0 : (blockIdx.z == 1) ? O1 : O2;
    __shared__ unsigned short As[128 * 32];
    __shared__ unsigned short Bs[128 * 32];
    const int tid = threadIdx.x;
    const int rowBase = blockIdx.x * 128;
    const int colBase = blockIdx.y * 128;
    const int lane = tid & 63, w = tid >> 6;
    const int wr = w >> 1, wc = w & 1;
    const int lr = lane & 15, kg = lane >> 4;
    const int srow = tid >> 1;
    const int scol = (tid & 1) * 16;

    f32x4 acc[4][4];
    const f32x4 zero = {0.f, 0.f, 0.f, 0.f};
    #pragma unroll
    for (int i = 0; i < 4; ++i)
        #pragma unroll
        for (int j = 0; j < 4; ++j) acc[i][j] = zero;

    const float* Arow = &X[(size_t)(rowBase + srow) * K + scol];
    const float* Brow = &W[(size_t)(colBase + srow) * K + scol];
    unsigned short* Adst = &As[srow * 32 + scol];
    unsigned short* Bdst = &Bs[srow * 32 + scol];

    for (int kb = 0; kb < K; kb += 32) {
        __syncthreads();
        stage16(Adst, Arow + kb);
        stage16(Bdst, Brow + kb);
        __syncthreads();
        bf16x8 af[4], bfr[4];
        #pragma unroll
        for (int mi = 0; mi < 4; ++mi)
            af[mi] = *(const bf16x8*)&As[(wr * 64 + mi * 16 + lr) * 32 + kg * 8];
        #pragma unroll
        for (int ni = 0; ni < 4; ++ni)
            bfr[ni] = *(const bf16x8*)&Bs[(wc * 64 + ni * 16 + lr) * 32 + kg * 8];
        #pragma unroll
        for (int mi = 0; mi < 4; ++mi)
            #pragma unroll
            for (int ni = 0; ni < 4; ++ni)
                acc[mi][ni] = __builtin_amdgcn_mfma_f32_16x16x32_bf16(af[mi], bfr[ni], acc[mi][ni], 0, 0, 0);
    }
    // Epilogue: D row = (lane>>4)*4 + j, col = lane&15  [verified m89/m91]
    #pragma unroll
    for (int mi = 0; mi < 4; ++mi)
        #pragma unroll
        for (int ni = 0; ni < 4; ++ni) {
            const int row0 = rowBase + wr * 64 + mi * 16 + kg * 4;
            const int col = colBase + wc * 64 + ni * 16 + lr;
            #pragma unroll
            for (int j = 0; j < 4; ++j)
                C[(size_t)(row0 + j) * N + col] = f2b(acc[mi][ni][j]);
        }
}

// ---------------------------------------------------------------------------
// 4) Attention: one block per (b,n). Stage q + 16 neighbor k/v rows in LDS,
//    thread (h,kk) computes a score, 16-lane shuffle softmax, then PV.
// ---------------------------------------------------------------------------
__global__ __launch_bounds__(256) void attn_kernel(
    const unsigned short* __restrict__ Q, const unsigned short* __restrict__ Kb,
    const unsigned short* __restrict__ Vb, const int* __restrict__ nbr,
    float* __restrict__ out)
{
    const int n = blockIdx.x;
    const int b = blockIdx.y;
    __shared__ unsigned short q_s[DMODEL];
    __shared__ unsigned short k_s[KNN][1028];   // pad -> ~4-way instead of 16-way
    __shared__ unsigned short v_s[KNN][DMODEL];
    __shared__ float a_s[NHEAD][KNN];
    __shared__ int nb_s[KNN];
    const int tid = threadIdx.x;
    if (tid < KNN) nb_s[tid] = nbr[n * KNN + tid];
    *(int2*)&q_s[tid * 4] = *(const int2*)&Q[((size_t)b * NPTS + n) * DMODEL + tid * 4];
    __syncthreads();
    #pragma unroll
    for (int kk = 0; kk < KNN; ++kk) {
        const int j = nb_s[kk];
        const size_t base = ((size_t)b * NPTS + j) * DMODEL;
        *(int2*)&k_s[kk][tid * 4] = *(const int2*)&Kb[base + tid * 4];
        *(int2*)&v_s[kk][tid * 4] = *(const int2*)&Vb[base + tid * 4];
    }
    __syncthreads();
    const int h = tid >> 4, kk = tid & 15;
    const unsigned short* qp = &q_s[h * HDIM];
    const unsigned short* kp = &k_s[kk][h * HDIM];
    float s = 0.f;
    #pragma unroll
    for (int d = 0; d < HDIM; ++d) s += b2f(qp[d]) * b2f(kp[d]);
    s *= 0.125f;  // 1/sqrt(64)
    float m = s;
    #pragma unroll
    for (int off = 8; off >= 1; off >>= 1) m = fmaxf(m, __shfl_xor(m, off, 16));
    const float e = __expf(s - m);
    float sum = e;
    #pragma unroll
    for (int off = 8; off >= 1; off >>= 1) sum += __shfl_xor(sum, off, 16);
    a_s[h][kk] = e / sum;
    __syncthreads();
    const size_t obase = ((size_t)b * NPTS + n) * DMODEL;
    #pragma unroll
    for (int r = 0; r < 4; ++r) {
        const int o = tid + 256 * r;
        const int h2 = o >> 6;
        float accv = 0.f;
        #pragma unroll
        for (int k2 = 0; k2 < KNN; ++k2) accv += a_s[h2][k2] * b2f(v_s[k2][o]);
        out[obase + o] = accv;
    }
}

// ---------------------------------------------------------------------------
// 5) metric = k.mean(axis=H): out2[b,n,d] = (1/16) sum_h k[b,n,h*64+d]
// ---------------------------------------------------------------------------
__global__ __launch_bounds__(256) void metric_kernel(const unsigned short* __restrict__ Kb,
                                                     float* __restrict__ mout) {
    const int i = blockIdx.x * 256 + threadIdx.x;
    if (i >= BATCH * NPTS * HDIM) return;
    const int d = i & 63;
    const int bn = i >> 6;
    const unsigned short* kp = &Kb[(size_t)bn * DMODEL + d];
    float s = 0.f;
    #pragma unroll
    for (int hh = 0; hh < NHEAD; ++hh) s += b2f(kp[hh * HDIM]);
    mout[i] = s * 0.0625f;
}

// ---------------------------------------------------------------------------
extern "C" void kernel_launch(void* const* d_in, const int* in_sizes, int n_in,
                              void* d_out, int out_size, void* d_ws, size_t ws_size,
                              hipStream_t stream) {
    const float* x = (const float*)d_in[0];
    const unsigned char* mask = (const unsigned char*)d_in[1];
    const float* Wq = (const float*)d_in[2];
    const float* Wk = (const float*)d_in[3];
    const float* Wv = (const float*)d_in[4];
    float* out = (float*)d_out;
    char* ws = (char*)d_ws;

    const size_t QKV_BYTES = (size_t)BATCH * NPTS * DMODEL * 2;  // 16 MB each
    unsigned short* qb = (unsigned short*)(ws);
    unsigned short* kb = (unsigned short*)(ws + QKV_BYTES);
    unsigned short* vb = (unsigned short*)(ws + 2 * QKV_BYTES);
    int* act = (int*)(ws + 3 * QKV_BYTES);
    int* nbr = (int*)(ws + 3 * QKV_BYTES + NPTS * sizeof(int));
    if (ws_size < 3 * QKV_BYTES + (size_t)NPTS * sizeof(int) * (1 + KNN)) return;

    extract_active<<<1, 1024, 0, stream>>>(mask, act);
    knn_kernel<<<256, 256, 0, stream>>>(act, nbr);
    gemm_qkv<<<dim3(64, 8, 3), 256, 0, stream>>>(x, Wq, Wk, Wv, qb, kb, vb);
    attn_kernel<<<dim3(NPTS, BATCH), 256, 0, stream>>>(qb, kb, vb, nbr, out);
    metric_kernel<<<(BATCH * NPTS * HDIM + 255) / 256, 256, 0, stream>>>(kb, out + (size_t)BATCH * NPTS * DMODEL);
}

// Round 3
// 311.379 us; speedup vs baseline: 1.4061x; 1.0794x over previous
//
#include <hip/hip_runtime.h>
#include <hip/hip_bf16.h>
#include <stdint.h>

// Problem constants
#define BATCH 2
#define NPTS 4096
#define DMODEL 1024
#define NHEAD 16
#define HDIM 64
#define KNN 16
#define MASKN 131072   // 32*64*64
#define BK 64

typedef __attribute__((ext_vector_type(8))) short bf16x8;
typedef __attribute__((ext_vector_type(4))) float f32x4;

__device__ __forceinline__ float b2f(unsigned short u) {
    union { unsigned int i; float f; } c; c.i = ((unsigned int)u) << 16; return c.f;
}
__device__ __forceinline__ unsigned short f2b(float f) {
    unsigned int x = __float_as_uint(f);
    unsigned int r = (x + 0x7fffu + ((x >> 16) & 1u)) >> 16;
    return (unsigned short)r;
}
__device__ __forceinline__ unsigned int pack2f(float a, float b) {
    return (unsigned int)f2b(a) | ((unsigned int)f2b(b) << 16);
}
// async global->LDS, 16B per lane. lptr must be wave-uniform; HW writes lptr + lane*16.
__device__ __forceinline__ void gload16(const unsigned short* g, unsigned short* l) {
    __builtin_amdgcn_global_load_lds((const __attribute__((address_space(1))) void*)g,
                                     (__attribute__((address_space(3))) void*)l, 16, 0, 0);
}

// ---------------------------------------------------------------------------
// 1) Extract active indices from mask (handles bool-byte or int32 storage)
// ---------------------------------------------------------------------------
__global__ __launch_bounds__(1024) void extract_active(const unsigned char* __restrict__ m8,
                                                       int* __restrict__ act) {
    __shared__ int sc[1024];
    __shared__ int s_total;
    const int t = threadIdx.x;
    const int chunk = MASKN / 1024;  // 128
    int cnt = 0;
    for (int i = 0; i < chunk; ++i) cnt += (m8[t * chunk + i] != 0) ? 1 : 0;
    sc[t] = cnt; __syncthreads();
    for (int off = 1; off < 1024; off <<= 1) {
        int v = (t >= off) ? sc[t - off] : 0;
        __syncthreads();
        sc[t] += v;
        __syncthreads();
    }
    if (t == 1023) s_total = sc[1023];
    __syncthreads();
    if (s_total == NPTS) {
        int pos = sc[t] - cnt;
        for (int i = 0; i < chunk; ++i) {
            int g = t * chunk + i;
            if (m8[g]) act[pos++] = g;
        }
    } else {
        const int* m32 = (const int*)m8;
        int cnt2 = 0;
        for (int i = 0; i < chunk; ++i) cnt2 += (m32[t * chunk + i] != 0) ? 1 : 0;
        __syncthreads();
        sc[t] = cnt2; __syncthreads();
        for (int off = 1; off < 1024; off <<= 1) {
            int v = (t >= off) ? sc[t - off] : 0;
            __syncthreads();
            sc[t] += v;
            __syncthreads();
        }
        int pos = sc[t] - cnt2;
        for (int i = 0; i < chunk; ++i) {
            int g = t * chunk + i;
            if (m32[g]) act[pos++] = g;
        }
    }
}

// ---------------------------------------------------------------------------
// 2) kNN: 16 threads/query, 16 queries/block -> 256 blocks.
// ---------------------------------------------------------------------------
__global__ __launch_bounds__(256) void knn_kernel(const int* __restrict__ act,
                                                  int* __restrict__ nbr) {
    __shared__ int act_s[NPTS];
    const int t = threadIdx.x;
    for (int i = t; i < NPTS; i += 256) act_s[i] = act[i];
    __syncthreads();
    const int q = blockIdx.x * 16 + (t >> 4);
    const int sub = t & 15;
    const int aq = act_s[q];
    const int qz = aq >> 12, qy = (aq >> 6) & 63, qx = aq & 63;
    int best[17];
    #pragma unroll
    for (int i = 0; i < 17; ++i) best[i] = 0x7FFFFFFF;
    for (int j = sub; j < NPTS; j += 16) {
        const int aj = act_s[j];
        const int dz = (aj >> 12) - qz;
        const int dy = ((aj >> 6) & 63) - qy;
        const int dx = (aj & 63) - qx;
        const int d2 = dz * dz + dy * dy + dx * dx;
        int p = (d2 << 12) | j;
        if (p < best[16]) {
            #pragma unroll
            for (int u = 0; u < 17; ++u) {
                const bool lt = p < best[u];
                const int tmp = best[u];
                best[u] = lt ? p : best[u];
                p = lt ? tmp : p;
            }
        }
    }
    int head = best[0];
    int keep = 0;
    #pragma unroll
    for (int r = 0; r < KNN + 1; ++r) {
        int m = head;
        #pragma unroll
        for (int off = 8; off >= 1; off >>= 1) m = min(m, __shfl_xor(m, off, 16));
        if (sub == r - 1) keep = m;
        const bool win = (head == m);
        #pragma unroll
        for (int u = 0; u < 16; ++u) if (win) best[u] = best[u + 1];
        if (win) best[16] = 0x7FFFFFFF;
        head = best[0];
    }
    nbr[q * KNN + sub] = keep & 4095;
}

// ---------------------------------------------------------------------------
// 3a) f32 -> bf16 cast (memory-bound, 8 elems/thread)
// ---------------------------------------------------------------------------
__global__ __launch_bounds__(256) void cast_kernel(const float* __restrict__ src,
                                                   unsigned short* __restrict__ dst, int n8) {
    const int i = blockIdx.x * 256 + threadIdx.x;
    if (i >= n8) return;
    const float4 a = ((const float4*)src)[2 * i];
    const float4 b = ((const float4*)src)[2 * i + 1];
    uint4 w;
    w.x = pack2f(a.x, a.y); w.y = pack2f(a.z, a.w);
    w.z = pack2f(b.x, b.y); w.w = pack2f(b.z, b.w);
    ((uint4*)dst)[i] = w;
}

// ---------------------------------------------------------------------------
// 3b) QKV GEMM (m97 structure): C[m][n] = sum_k Xb[m][k] * Wb[n][k], all bf16.
//     128x128 tile, BK=64, global_load_lds width=16, linear LDS, 2-barrier.
// ---------------------------------------------------------------------------
__global__ __launch_bounds__(256) void gemm_qkv_bf16(
    const unsigned short* __restrict__ Xb,
    const unsigned short* __restrict__ Wb,   // 3 contiguous 1024x1024 bf16
    unsigned short* __restrict__ O0, unsigned short* __restrict__ O1, unsigned short* __restrict__ O2)
{
    const int K = DMODEL, N = DMODEL;
    const unsigned short* W = Wb + (size_t)blockIdx.z * DMODEL * DMODEL;
    unsigned short* C = (blockIdx.z == 0) ? O0 : (blockIdx.z == 1) ? O1 : O2;
    __shared__ unsigned short As[128 * BK];
    __shared__ unsigned short Bs[128 * BK];
    const int tid = threadIdx.x;
    const int rowBase = blockIdx.x * 128;
    const int colBase = blockIdx.y * 128;
    const int lane = tid & 63, w = tid >> 6;
    const int wr = w >> 1, wc = w & 1;
    const int lr = lane & 15, kg = lane >> 4;
    const int srow = tid >> 3;          // 0..31 (row within a 32-row staging chunk)
    const int scol = (tid & 7) * 8;     // element col within BK row

    f32x4 acc[4][4];
    const f32x4 zero = {0.f, 0.f, 0.f, 0.f};
    #pragma unroll
    for (int i = 0; i < 4; ++i)
        #pragma unroll
        for (int j = 0; j < 4; ++j) acc[i][j] = zero;

    const unsigned short* Ag = &Xb[(size_t)(rowBase + srow) * K + scol];
    const unsigned short* Bg = &W[(size_t)(colBase + srow) * K + scol];
    // wave-uniform LDS dest: rows (r*32 + wave*8), 64 shorts/row
    unsigned short* Al = &As[(size_t)(w * 8) * BK];
    unsigned short* Bl = &Bs[(size_t)(w * 8) * BK];

    for (int kb = 0; kb < K; kb += BK) {
        __syncthreads();
        #pragma unroll
        for (int r = 0; r < 4; ++r) {
            gload16(Ag + (size_t)(r * 32) * K + kb, Al + r * 32 * BK);
            gload16(Bg + (size_t)(r * 32) * K + kb, Bl + r * 32 * BK);
        }
        __syncthreads();   // drains vmcnt -> tile visible
        bf16x8 af[2][4], bfr[2][4];
        #pragma unroll
        for (int kk = 0; kk < 2; ++kk) {
            #pragma unroll
            for (int mi = 0; mi < 4; ++mi)
                af[kk][mi] = *(const bf16x8*)&As[(wr * 64 + mi * 16 + lr) * BK + kk * 32 + kg * 8];
            #pragma unroll
            for (int ni = 0; ni < 4; ++ni)
                bfr[kk][ni] = *(const bf16x8*)&Bs[(wc * 64 + ni * 16 + lr) * BK + kk * 32 + kg * 8];
        }
        #pragma unroll
        for (int kk = 0; kk < 2; ++kk)
            #pragma unroll
            for (int mi = 0; mi < 4; ++mi)
                #pragma unroll
                for (int ni = 0; ni < 4; ++ni)
                    acc[mi][ni] = __builtin_amdgcn_mfma_f32_16x16x32_bf16(af[kk][mi], bfr[kk][ni], acc[mi][ni], 0, 0, 0);
    }
    // Epilogue: D row = (lane>>4)*4 + j, col = lane&15
    #pragma unroll
    for (int mi = 0; mi < 4; ++mi)
        #pragma unroll
        for (int ni = 0; ni < 4; ++ni) {
            const int row0 = rowBase + wr * 64 + mi * 16 + kg * 4;
            const int col = colBase + wc * 64 + ni * 16 + lr;
            #pragma unroll
            for (int j = 0; j < 4; ++j)
                C[(size_t)(row0 + j) * N + col] = f2b(acc[mi][ni][j]);
        }
}

// ---------------------------------------------------------------------------
// 3c) FALLBACK f32-input GEMM (used only if ws too small for bf16 copies)
// ---------------------------------------------------------------------------
__device__ __forceinline__ void stage16(unsigned short* dst, const float* src) {
    const float4 a = ((const float4*)src)[0];
    const float4 b = ((const float4*)src)[1];
    const float4 c = ((const float4*)src)[2];
    const float4 d = ((const float4*)src)[3];
    uint4 w0, w1;
    w0.x = pack2f(a.x, a.y); w0.y = pack2f(a.z, a.w);
    w0.z = pack2f(b.x, b.y); w0.w = pack2f(b.z, b.w);
    w1.x = pack2f(c.x, c.y); w1.y = pack2f(c.z, c.w);
    w1.z = pack2f(d.x, d.y); w1.w = pack2f(d.z, d.w);
    ((uint4*)dst)[0] = w0;
    ((uint4*)dst)[1] = w1;
}

__global__ __launch_bounds__(256) void gemm_qkv_f32(
    const float* __restrict__ X,
    const float* __restrict__ W0, const float* __restrict__ W1, const float* __restrict__ W2,
    unsigned short* __restrict__ O0, unsigned short* __restrict__ O1, unsigned short* __restrict__ O2)
{
    const int K = DMODEL, N = DMODEL;
    const float* W = (blockIdx.z == 0) ? W0 : (blockIdx.z == 1) ? W1 : W2;
    unsigned short* C = (blockIdx.z == 0) ? O0 : (blockIdx.z == 1) ? O1 : O2;
    __shared__ unsigned short As[128 * 32];
    __shared__ unsigned short Bs[128 * 32];
    const int tid = threadIdx.x;
    const int rowBase = blockIdx.x * 128;
    const int colBase = blockIdx.y * 128;
    const int lane = tid & 63, w = tid >> 6;
    const int wr = w >> 1, wc = w & 1;
    const int lr = lane & 15, kg = lane >> 4;
    const int srow = tid >> 1;
    const int scol = (tid & 1) * 16;
    f32x4 acc[4][4];
    const f32x4 zero = {0.f, 0.f, 0.f, 0.f};
    #pragma unroll
    for (int i = 0; i < 4; ++i)
        #pragma unroll
        for (int j = 0; j < 4; ++j) acc[i][j] = zero;
    const float* Arow = &X[(size_t)(rowBase + srow) * K + scol];
    const float* Brow = &W[(size_t)(colBase + srow) * K + scol];
    unsigned short* Adst = &As[srow * 32 + scol];
    unsigned short* Bdst = &Bs[srow * 32 + scol];
    for (int kb = 0; kb < K; kb += 32) {
        __syncthreads();
        stage16(Adst, Arow + kb);
        stage16(Bdst, Brow + kb);
        __syncthreads();
        bf16x8 af[4], bfr[4];
        #pragma unroll
        for (int mi = 0; mi < 4; ++mi)
            af[mi] = *(const bf16x8*)&As[(wr * 64 + mi * 16 + lr) * 32 + kg * 8];
        #pragma unroll
        for (int ni = 0; ni < 4; ++ni)
            bfr[ni] = *(const bf16x8*)&Bs[(wc * 64 + ni * 16 + lr) * 32 + kg * 8];
        #pragma unroll
        for (int mi = 0; mi < 4; ++mi)
            #pragma unroll
            for (int ni = 0; ni < 4; ++ni)
                acc[mi][ni] = __builtin_amdgcn_mfma_f32_16x16x32_bf16(af[mi], bfr[ni], acc[mi][ni], 0, 0, 0);
    }
    #pragma unroll
    for (int mi = 0; mi < 4; ++mi)
        #pragma unroll
        for (int ni = 0; ni < 4; ++ni) {
            const int row0 = rowBase + wr * 64 + mi * 16 + kg * 4;
            const int col = colBase + wc * 64 + ni * 16 + lr;
            #pragma unroll
            for (int j = 0; j < 4; ++j)
                C[(size_t)(row0 + j) * N + col] = f2b(acc[mi][ni][j]);
        }
}

// ---------------------------------------------------------------------------
// 4) Attention: one block per (b,n).
// ---------------------------------------------------------------------------
__global__ __launch_bounds__(256) void attn_kernel(
    const unsigned short* __restrict__ Q, const unsigned short* __restrict__ Kb,
    const unsigned short* __restrict__ Vb, const int* __restrict__ nbr,
    float* __restrict__ out)
{
    const int n = blockIdx.x;
    const int b = blockIdx.y;
    __shared__ unsigned short q_s[DMODEL];
    __shared__ unsigned short k_s[KNN][1028];
    __shared__ unsigned short v_s[KNN][DMODEL];
    __shared__ float a_s[NHEAD][KNN];
    __shared__ int nb_s[KNN];
    const int tid = threadIdx.x;
    if (tid < KNN) nb_s[tid] = nbr[n * KNN + tid];
    *(int2*)&q_s[tid * 4] = *(const int2*)&Q[((size_t)b * NPTS + n) * DMODEL + tid * 4];
    __syncthreads();
    #pragma unroll
    for (int kk = 0; kk < KNN; ++kk) {
        const int j = nb_s[kk];
        const size_t base = ((size_t)b * NPTS + j) * DMODEL;
        *(int2*)&k_s[kk][tid * 4] = *(const int2*)&Kb[base + tid * 4];
        *(int2*)&v_s[kk][tid * 4] = *(const int2*)&Vb[base + tid * 4];
    }
    __syncthreads();
    const int h = tid >> 4, kk = tid & 15;
    const unsigned short* qp = &q_s[h * HDIM];
    const unsigned short* kp = &k_s[kk][h * HDIM];
    float s = 0.f;
    #pragma unroll
    for (int d = 0; d < HDIM; ++d) s += b2f(qp[d]) * b2f(kp[d]);
    s *= 0.125f;
    float m = s;
    #pragma unroll
    for (int off = 8; off >= 1; off >>= 1) m = fmaxf(m, __shfl_xor(m, off, 16));
    const float e = __expf(s - m);
    float sum = e;
    #pragma unroll
    for (int off = 8; off >= 1; off >>= 1) sum += __shfl_xor(sum, off, 16);
    a_s[h][kk] = e / sum;
    __syncthreads();
    const size_t obase = ((size_t)b * NPTS + n) * DMODEL;
    #pragma unroll
    for (int r = 0; r < 4; ++r) {
        const int o = tid + 256 * r;
        const int h2 = o >> 6;
        float accv = 0.f;
        #pragma unroll
        for (int k2 = 0; k2 < KNN; ++k2) accv += a_s[h2][k2] * b2f(v_s[k2][o]);
        out[obase + o] = accv;
    }
}

// ---------------------------------------------------------------------------
// 5) metric = k.mean(axis=H)
// ---------------------------------------------------------------------------
__global__ __launch_bounds__(256) void metric_kernel(const unsigned short* __restrict__ Kb,
                                                     float* __restrict__ mout) {
    const int i = blockIdx.x * 256 + threadIdx.x;
    if (i >= BATCH * NPTS * HDIM) return;
    const int d = i & 63;
    const int bn = i >> 6;
    const unsigned short* kp = &Kb[(size_t)bn * DMODEL + d];
    float s = 0.f;
    #pragma unroll
    for (int hh = 0; hh < NHEAD; ++hh) s += b2f(kp[hh * HDIM]);
    mout[i] = s * 0.0625f;
}

// ---------------------------------------------------------------------------
extern "C" void kernel_launch(void* const* d_in, const int* in_sizes, int n_in,
                              void* d_out, int out_size, void* d_ws, size_t ws_size,
                              hipStream_t stream) {
    const float* x = (const float*)d_in[0];
    const unsigned char* mask = (const unsigned char*)d_in[1];
    const float* Wq = (const float*)d_in[2];
    const float* Wk = (const float*)d_in[3];
    const float* Wv = (const float*)d_in[4];
    float* out = (float*)d_out;
    char* ws = (char*)d_ws;

    const size_t QKV_BYTES = (size_t)BATCH * NPTS * DMODEL * 2;   // 16.78 MB each
    const size_t XB_BYTES  = (size_t)BATCH * NPTS * DMODEL * 2;   // 16.78 MB
    const size_t WB_BYTES  = (size_t)3 * DMODEL * DMODEL * 2;     // 6.29 MB
    unsigned short* qb = (unsigned short*)(ws);
    unsigned short* kb = (unsigned short*)(ws + QKV_BYTES);
    unsigned short* vb = (unsigned short*)(ws + 2 * QKV_BYTES);
    const size_t need_base = 3 * QKV_BYTES + (size_t)NPTS * sizeof(int) * (1 + KNN);
    const size_t need_full = need_base + XB_BYTES + WB_BYTES;
    const bool full = (ws_size >= need_full);
    char* tail = ws + 3 * QKV_BYTES;
    unsigned short* Xb = (unsigned short*)tail;
    unsigned short* Wb = (unsigned short*)(tail + XB_BYTES);
    char* small = full ? (tail + XB_BYTES + WB_BYTES) : tail;
    int* act = (int*)small;
    int* nbr = (int*)(small + NPTS * sizeof(int));
    if (ws_size < need_base) return;

    extract_active<<<1, 1024, 0, stream>>>(mask, act);
    knn_kernel<<<256, 256, 0, stream>>>(act, nbr);
    if (full) {
        const int xn8 = BATCH * NPTS * DMODEL / 8;     // 1048576
        const int wn8 = DMODEL * DMODEL / 8;           // 131072
        cast_kernel<<<(xn8 + 255) / 256, 256, 0, stream>>>(x, Xb, xn8);
        cast_kernel<<<(wn8 + 255) / 256, 256, 0, stream>>>(Wq, Wb, wn8);
        cast_kernel<<<(wn8 + 255) / 256, 256, 0, stream>>>(Wk, Wb + (size_t)DMODEL * DMODEL, wn8);
        cast_kernel<<<(wn8 + 255) / 256, 256, 0, stream>>>(Wv, Wb + (size_t)2 * DMODEL * DMODEL, wn8);
        gemm_qkv_bf16<<<dim3(64, 8, 3), 256, 0, stream>>>(Xb, Wb, qb, kb, vb);
    } else {
        gemm_qkv_f32<<<dim3(64, 8, 3), 256, 0, stream>>>(x, Wq, Wk, Wv, qb, kb, vb);
    }
    attn_kernel<<<dim3(NPTS, BATCH), 256, 0, stream>>>(qb, kb, vb, nbr, out);
    metric_kernel<<<(BATCH * NPTS * HDIM + 255) / 256, 256, 0, stream>>>(kb, out + (size_t)BATCH * NPTS * DMODEL);
}

// Round 4
// 228.002 us; speedup vs baseline: 1.9203x; 1.3657x over previous
//
#include <hip/hip_runtime.h>
#include <hip/hip_bf16.h>
#include <stdint.h>

// Problem constants
#define BATCH 2
#define NPTS 4096
#define DMODEL 1024
#define NHEAD 16
#define HDIM 64
#define KNN 16
#define MASKN 131072   // 32*64*64
#define BK 64
#define EBLK 128       // extraction blocks (1024 mask elems each)

typedef __attribute__((ext_vector_type(8))) short bf16x8;
typedef __attribute__((ext_vector_type(4))) float f32x4;

__device__ __forceinline__ float b2f(unsigned short u) {
    union { unsigned int i; float f; } c; c.i = ((unsigned int)u) << 16; return c.f;
}
__device__ __forceinline__ unsigned short f2b(float f) {
    unsigned int x = __float_as_uint(f);
    unsigned int r = (x + 0x7fffu + ((x >> 16) & 1u)) >> 16;
    return (unsigned short)r;
}
__device__ __forceinline__ unsigned int pack2f(float a, float b) {
    return (unsigned int)f2b(a) | ((unsigned int)f2b(b) << 16);
}
// async global->LDS, 16B per lane. lptr must be wave-uniform; HW writes lptr + lane*16.
__device__ __forceinline__ void gload16(const unsigned short* g, unsigned short* l) {
    __builtin_amdgcn_global_load_lds((const __attribute__((address_space(1))) void*)g,
                                     (__attribute__((address_space(3))) void*)l, 16, 0, 0);
}

// ---------------------------------------------------------------------------
// 1) Parallel active-index extraction (3 tiny kernels, no atomics, OOB-safe)
// ---------------------------------------------------------------------------
__global__ __launch_bounds__(256) void count8_kernel(const unsigned char* __restrict__ m8,
                                                     int* __restrict__ cnt8) {
    __shared__ int red[256];
    const int b = blockIdx.x, t = threadIdx.x;
    const uchar4 v = ((const uchar4*)m8)[b * 256 + t];
    red[t] = (v.x != 0) + (v.y != 0) + (v.z != 0) + (v.w != 0);
    __syncthreads();
    for (int off = 128; off >= 1; off >>= 1) {
        if (t < off) red[t] += red[t + off];
        __syncthreads();
    }
    if (t == 0) cnt8[b] = red[0];
}

__global__ __launch_bounds__(256) void count32_kernel(const unsigned char* __restrict__ m8,
                                                      const int* __restrict__ cnt8,
                                                      int* __restrict__ cnt32) {
    __shared__ int red[256];
    const int b = blockIdx.x, t = threadIdx.x;
    red[t] = (t < EBLK) ? cnt8[t] : 0;
    __syncthreads();
    for (int off = 128; off >= 1; off >>= 1) {
        if (t < off) red[t] += red[t + off];
        __syncthreads();
    }
    if (red[0] == NPTS) return;     // mask is byte-bool; int view would be OOB
    __syncthreads();
    const int4 v = ((const int4*)m8)[b * 256 + t];
    red[t] = (v.x != 0) + (v.y != 0) + (v.z != 0) + (v.w != 0);
    __syncthreads();
    for (int off = 128; off >= 1; off >>= 1) {
        if (t < off) red[t] += red[t + off];
        __syncthreads();
    }
    if (t == 0) cnt32[b] = red[0];
}

__global__ __launch_bounds__(256) void extract_kernel(const unsigned char* __restrict__ m8,
                                                      const int* __restrict__ cnt8,
                                                      const int* __restrict__ cnt32,
                                                      int* __restrict__ act) {
    __shared__ int sblk[EBLK];
    __shared__ int sthr[256];
    const int b = blockIdx.x, t = threadIdx.x;
    if (t < EBLK) sblk[t] = cnt8[t];
    __syncthreads();
    for (int off = 1; off < EBLK; off <<= 1) {
        int v = (t < EBLK && t >= off) ? sblk[t - off] : 0;
        __syncthreads();
        if (t < EBLK) sblk[t] += v;
        __syncthreads();
    }
    const bool bytes = (sblk[EBLK - 1] == NPTS);   // grid-uniform
    if (!bytes) {
        __syncthreads();
        if (t < EBLK) sblk[t] = cnt32[t];
        __syncthreads();
        for (int off = 1; off < EBLK; off <<= 1) {
            int v = (t < EBLK && t >= off) ? sblk[t - off] : 0;
            __syncthreads();
            if (t < EBLK) sblk[t] += v;
            __syncthreads();
        }
    }
    const int blkoff = (b == 0) ? 0 : sblk[b - 1];
    const int gbase = b * 1024 + t * 4;
    int f0, f1, f2, f3;
    if (bytes) {
        const uchar4 v = ((const uchar4*)m8)[b * 256 + t];
        f0 = v.x != 0; f1 = v.y != 0; f2 = v.z != 0; f3 = v.w != 0;
    } else {
        const int4 v = ((const int4*)m8)[b * 256 + t];
        f0 = v.x != 0; f1 = v.y != 0; f2 = v.z != 0; f3 = v.w != 0;
    }
    const int c = f0 + f1 + f2 + f3;
    sthr[t] = c;
    __syncthreads();
    for (int off = 1; off < 256; off <<= 1) {
        int v = (t >= off) ? sthr[t - off] : 0;
        __syncthreads();
        sthr[t] += v;
        __syncthreads();
    }
    int pos = blkoff + sthr[t] - c;
    if (f0) act[pos++] = gbase;
    if (f1) act[pos++] = gbase + 1;
    if (f2) act[pos++] = gbase + 2;
    if (f3) act[pos++] = gbase + 3;
}

// ---------------------------------------------------------------------------
// 2) kNN: 16 threads/query, 16 queries/block -> 256 blocks.
// ---------------------------------------------------------------------------
__global__ __launch_bounds__(256) void knn_kernel(const int* __restrict__ act,
                                                  int* __restrict__ nbr) {
    __shared__ int act_s[NPTS];
    const int t = threadIdx.x;
    for (int i = t; i < NPTS; i += 256) act_s[i] = act[i];
    __syncthreads();
    const int q = blockIdx.x * 16 + (t >> 4);
    const int sub = t & 15;
    const int aq = act_s[q];
    const int qz = aq >> 12, qy = (aq >> 6) & 63, qx = aq & 63;
    int best[17];
    #pragma unroll
    for (int i = 0; i < 17; ++i) best[i] = 0x7FFFFFFF;
    for (int j = sub; j < NPTS; j += 16) {
        const int aj = act_s[j];
        const int dz = (aj >> 12) - qz;
        const int dy = ((aj >> 6) & 63) - qy;
        const int dx = (aj & 63) - qx;
        const int d2 = dz * dz + dy * dy + dx * dx;
        int p = (d2 << 12) | j;
        if (p < best[16]) {
            #pragma unroll
            for (int u = 0; u < 17; ++u) {
                const bool lt = p < best[u];
                const int tmp = best[u];
                best[u] = lt ? p : best[u];
                p = lt ? tmp : p;
            }
        }
    }
    int head = best[0];
    int keep = 0;
    #pragma unroll
    for (int r = 0; r < KNN + 1; ++r) {
        int m = head;
        #pragma unroll
        for (int off = 8; off >= 1; off >>= 1) m = min(m, __shfl_xor(m, off, 16));
        if (sub == r - 1) keep = m;
        const bool win = (head == m);
        #pragma unroll
        for (int u = 0; u < 16; ++u) if (win) best[u] = best[u + 1];
        if (win) best[16] = 0x7FFFFFFF;
        head = best[0];
    }
    nbr[q * KNN + sub] = keep & 4095;
}

// ---------------------------------------------------------------------------
// 3a) f32 -> bf16 cast (memory-bound, 8 elems/thread)
// ---------------------------------------------------------------------------
__global__ __launch_bounds__(256) void cast_kernel(const float* __restrict__ src,
                                                   unsigned short* __restrict__ dst, int n8) {
    const int i = blockIdx.x * 256 + threadIdx.x;
    if (i >= n8) return;
    const float4 a = ((const float4*)src)[2 * i];
    const float4 b = ((const float4*)src)[2 * i + 1];
    uint4 w;
    w.x = pack2f(a.x, a.y); w.y = pack2f(a.z, a.w);
    w.z = pack2f(b.x, b.y); w.w = pack2f(b.z, b.w);
    ((uint4*)dst)[i] = w;
}

// ---------------------------------------------------------------------------
// 3b) QKV GEMM (m97 structure): C[m][n] = sum_k Xb[m][k] * Wb[n][k], all bf16.
// ---------------------------------------------------------------------------
__global__ __launch_bounds__(256) void gemm_qkv_bf16(
    const unsigned short* __restrict__ Xb,
    const unsigned short* __restrict__ Wb,   // 3 contiguous 1024x1024 bf16
    unsigned short* __restrict__ O0, unsigned short* __restrict__ O1, unsigned short* __restrict__ O2)
{
    const int K = DMODEL, N = DMODEL;
    const unsigned short* W = Wb + (size_t)blockIdx.z * DMODEL * DMODEL;
    unsigned short* C = (blockIdx.z == 0) ? O0 : (blockIdx.z == 1) ? O1 : O2;
    __shared__ unsigned short As[128 * BK];
    __shared__ unsigned short Bs[128 * BK];
    const int tid = threadIdx.x;
    const int rowBase = blockIdx.x * 128;
    const int colBase = blockIdx.y * 128;
    const int lane = tid & 63, w = tid >> 6;
    const int wr = w >> 1, wc = w & 1;
    const int lr = lane & 15, kg = lane >> 4;
    const int srow = tid >> 3;
    const int scol = (tid & 7) * 8;

    f32x4 acc[4][4];
    const f32x4 zero = {0.f, 0.f, 0.f, 0.f};
    #pragma unroll
    for (int i = 0; i < 4; ++i)
        #pragma unroll
        for (int j = 0; j < 4; ++j) acc[i][j] = zero;

    const unsigned short* Ag = &Xb[(size_t)(rowBase + srow) * K + scol];
    const unsigned short* Bg = &W[(size_t)(colBase + srow) * K + scol];
    unsigned short* Al = &As[(size_t)(w * 8) * BK];
    unsigned short* Bl = &Bs[(size_t)(w * 8) * BK];

    for (int kb = 0; kb < K; kb += BK) {
        __syncthreads();
        #pragma unroll
        for (int r = 0; r < 4; ++r) {
            gload16(Ag + (size_t)(r * 32) * K + kb, Al + r * 32 * BK);
            gload16(Bg + (size_t)(r * 32) * K + kb, Bl + r * 32 * BK);
        }
        __syncthreads();
        bf16x8 af[2][4], bfr[2][4];
        #pragma unroll
        for (int kk = 0; kk < 2; ++kk) {
            #pragma unroll
            for (int mi = 0; mi < 4; ++mi)
                af[kk][mi] = *(const bf16x8*)&As[(wr * 64 + mi * 16 + lr) * BK + kk * 32 + kg * 8];
            #pragma unroll
            for (int ni = 0; ni < 4; ++ni)
                bfr[kk][ni] = *(const bf16x8*)&Bs[(wc * 64 + ni * 16 + lr) * BK + kk * 32 + kg * 8];
        }
        #pragma unroll
        for (int kk = 0; kk < 2; ++kk)
            #pragma unroll
            for (int mi = 0; mi < 4; ++mi)
                #pragma unroll
                for (int ni = 0; ni < 4; ++ni)
                    acc[mi][ni] = __builtin_amdgcn_mfma_f32_16x16x32_bf16(af[kk][mi], bfr[kk][ni], acc[mi][ni], 0, 0, 0);
    }
    #pragma unroll
    for (int mi = 0; mi < 4; ++mi)
        #pragma unroll
        for (int ni = 0; ni < 4; ++ni) {
            const int row0 = rowBase + wr * 64 + mi * 16 + kg * 4;
            const int col = colBase + wc * 64 + ni * 16 + lr;
            #pragma unroll
            for (int j = 0; j < 4; ++j)
                C[(size_t)(row0 + j) * N + col] = f2b(acc[mi][ni][j]);
        }
}

// ---------------------------------------------------------------------------
// 3c) FALLBACK f32-input GEMM (used only if ws too small for bf16 copies)
// ---------------------------------------------------------------------------
__device__ __forceinline__ void stage16(unsigned short* dst, const float* src) {
    const float4 a = ((const float4*)src)[0];
    const float4 b = ((const float4*)src)[1];
    const float4 c = ((const float4*)src)[2];
    const float4 d = ((const float4*)src)[3];
    uint4 w0, w1;
    w0.x = pack2f(a.x, a.y); w0.y = pack2f(a.z, a.w);
    w0.z = pack2f(b.x, b.y); w0.w = pack2f(b.z, b.w);
    w1.x = pack2f(c.x, c.y); w1.y = pack2f(c.z, c.w);
    w1.z = pack2f(d.x, d.y); w1.w = pack2f(d.z, d.w);
    ((uint4*)dst)[0] = w0;
    ((uint4*)dst)[1] = w1;
}

__global__ __launch_bounds__(256) void gemm_qkv_f32(
    const float* __restrict__ X,
    const float* __restrict__ W0, const float* __restrict__ W1, const float* __restrict__ W2,
    unsigned short* __restrict__ O0, unsigned short* __restrict__ O1, unsigned short* __restrict__ O2)
{
    const int K = DMODEL, N = DMODEL;
    const float* W = (blockIdx.z == 0) ? W0 : (blockIdx.z == 1) ? W1 : W2;
    unsigned short* C = (blockIdx.z == 0) ? O0 : (blockIdx.z == 1) ? O1 : O2;
    __shared__ unsigned short As[128 * 32];
    __shared__ unsigned short Bs[128 * 32];
    const int tid = threadIdx.x;
    const int rowBase = blockIdx.x * 128;
    const int colBase = blockIdx.y * 128;
    const int lane = tid & 63, w = tid >> 6;
    const int wr = w >> 1, wc = w & 1;
    const int lr = lane & 15, kg = lane >> 4;
    const int srow = tid >> 1;
    const int scol = (tid & 1) * 16;
    f32x4 acc[4][4];
    const f32x4 zero = {0.f, 0.f, 0.f, 0.f};
    #pragma unroll
    for (int i = 0; i < 4; ++i)
        #pragma unroll
        for (int j = 0; j < 4; ++j) acc[i][j] = zero;
    const float* Arow = &X[(size_t)(rowBase + srow) * K + scol];
    const float* Brow = &W[(size_t)(colBase + srow) * K + scol];
    unsigned short* Adst = &As[srow * 32 + scol];
    unsigned short* Bdst = &Bs[srow * 32 + scol];
    for (int kb = 0; kb < K; kb += 32) {
        __syncthreads();
        stage16(Adst, Arow + kb);
        stage16(Bdst, Brow + kb);
        __syncthreads();
        bf16x8 af[4], bfr[4];
        #pragma unroll
        for (int mi = 0; mi < 4; ++mi)
            af[mi] = *(const bf16x8*)&As[(wr * 64 + mi * 16 + lr) * 32 + kg * 8];
        #pragma unroll
        for (int ni = 0; ni < 4; ++ni)
            bfr[ni] = *(const bf16x8*)&Bs[(wc * 64 + ni * 16 + lr) * 32 + kg * 8];
        #pragma unroll
        for (int mi = 0; mi < 4; ++mi)
            #pragma unroll
            for (int ni = 0; ni < 4; ++ni)
                acc[mi][ni] = __builtin_amdgcn_mfma_f32_16x16x32_bf16(af[mi], bfr[ni], acc[mi][ni], 0, 0, 0);
    }
    #pragma unroll
    for (int mi = 0; mi < 4; ++mi)
        #pragma unroll
        for (int ni = 0; ni < 4; ++ni) {
            const int row0 = rowBase + wr * 64 + mi * 16 + kg * 4;
            const int col = colBase + wc * 64 + ni * 16 + lr;
            #pragma unroll
            for (int j = 0; j < 4; ++j)
                C[(size_t)(row0 + j) * N + col] = f2b(acc[mi][ni][j]);
        }
}

// ---------------------------------------------------------------------------
// 4) Attention: one block per (b,n).
// ---------------------------------------------------------------------------
__global__ __launch_bounds__(256) void attn_kernel(
    const unsigned short* __restrict__ Q, const unsigned short* __restrict__ Kb,
    const unsigned short* __restrict__ Vb, const int* __restrict__ nbr,
    float* __restrict__ out)
{
    const int n = blockIdx.x;
    const int b = blockIdx.y;
    __shared__ unsigned short q_s[DMODEL];
    __shared__ unsigned short k_s[KNN][1028];
    __shared__ unsigned short v_s[KNN][DMODEL];
    __shared__ float a_s[NHEAD][KNN];
    __shared__ int nb_s[KNN];
    const int tid = threadIdx.x;
    if (tid < KNN) nb_s[tid] = nbr[n * KNN + tid];
    *(int2*)&q_s[tid * 4] = *(const int2*)&Q[((size_t)b * NPTS + n) * DMODEL + tid * 4];
    __syncthreads();
    #pragma unroll
    for (int kk = 0; kk < KNN; ++kk) {
        const int j = nb_s[kk];
        const size_t base = ((size_t)b * NPTS + j) * DMODEL;
        *(int2*)&k_s[kk][tid * 4] = *(const int2*)&Kb[base + tid * 4];
        *(int2*)&v_s[kk][tid * 4] = *(const int2*)&Vb[base + tid * 4];
    }
    __syncthreads();
    const int h = tid >> 4, kk = tid & 15;
    const unsigned short* qp = &q_s[h * HDIM];
    const unsigned short* kp = &k_s[kk][h * HDIM];
    float s = 0.f;
    #pragma unroll
    for (int d = 0; d < HDIM; ++d) s += b2f(qp[d]) * b2f(kp[d]);
    s *= 0.125f;
    float m = s;
    #pragma unroll
    for (int off = 8; off >= 1; off >>= 1) m = fmaxf(m, __shfl_xor(m, off, 16));
    const float e = __expf(s - m);
    float sum = e;
    #pragma unroll
    for (int off = 8; off >= 1; off >>= 1) sum += __shfl_xor(sum, off, 16);
    a_s[h][kk] = e / sum;
    __syncthreads();
    const size_t obase = ((size_t)b * NPTS + n) * DMODEL;
    #pragma unroll
    for (int r = 0; r < 4; ++r) {
        const int o = tid + 256 * r;
        const int h2 = o >> 6;
        float accv = 0.f;
        #pragma unroll
        for (int k2 = 0; k2 < KNN; ++k2) accv += a_s[h2][k2] * b2f(v_s[k2][o]);
        out[obase + o] = accv;
    }
}

// ---------------------------------------------------------------------------
// 5) metric = k.mean(axis=H)
// ---------------------------------------------------------------------------
__global__ __launch_bounds__(256) void metric_kernel(const unsigned short* __restrict__ Kb,
                                                     float* __restrict__ mout) {
    const int i = blockIdx.x * 256 + threadIdx.x;
    if (i >= BATCH * NPTS * HDIM) return;
    const int d = i & 63;
    const int bn = i >> 6;
    const unsigned short* kp = &Kb[(size_t)bn * DMODEL + d];
    float s = 0.f;
    #pragma unroll
    for (int hh = 0; hh < NHEAD; ++hh) s += b2f(kp[hh * HDIM]);
    mout[i] = s * 0.0625f;
}

// ---------------------------------------------------------------------------
extern "C" void kernel_launch(void* const* d_in, const int* in_sizes, int n_in,
                              void* d_out, int out_size, void* d_ws, size_t ws_size,
                              hipStream_t stream) {
    const float* x = (const float*)d_in[0];
    const unsigned char* mask = (const unsigned char*)d_in[1];
    const float* Wq = (const float*)d_in[2];
    const float* Wk = (const float*)d_in[3];
    const float* Wv = (const float*)d_in[4];
    float* out = (float*)d_out;
    char* ws = (char*)d_ws;

    const size_t QKV_BYTES = (size_t)BATCH * NPTS * DMODEL * 2;   // 16.78 MB each
    const size_t XB_BYTES  = (size_t)BATCH * NPTS * DMODEL * 2;   // 16.78 MB
    const size_t WB_BYTES  = (size_t)3 * DMODEL * DMODEL * 2;     // 6.29 MB
    unsigned short* qb = (unsigned short*)(ws);
    unsigned short* kb = (unsigned short*)(ws + QKV_BYTES);
    unsigned short* vb = (unsigned short*)(ws + 2 * QKV_BYTES);
    const size_t SMALL_BYTES = (size_t)NPTS * sizeof(int) * (1 + KNN) + 2 * EBLK * sizeof(int);
    const size_t need_base = 3 * QKV_BYTES + SMALL_BYTES;
    const size_t need_full = need_base + XB_BYTES + WB_BYTES;
    const bool full = (ws_size >= need_full);
    char* tail = ws + 3 * QKV_BYTES;
    unsigned short* Xb = (unsigned short*)tail;
    unsigned short* Wb = (unsigned short*)(tail + XB_BYTES);
    char* small = full ? (tail + XB_BYTES + WB_BYTES) : tail;
    int* act  = (int*)small;
    int* nbr  = (int*)(small + NPTS * sizeof(int));
    int* cnt8 = (int*)(small + NPTS * sizeof(int) * (1 + KNN));
    int* cnt32 = cnt8 + EBLK;
    if (ws_size < need_base) return;

    count8_kernel<<<EBLK, 256, 0, stream>>>(mask, cnt8);
    count32_kernel<<<EBLK, 256, 0, stream>>>(mask, cnt8, cnt32);
    extract_kernel<<<EBLK, 256, 0, stream>>>(mask, cnt8, cnt32, act);
    knn_kernel<<<256, 256, 0, stream>>>(act, nbr);
    if (full) {
        const int xn8 = BATCH * NPTS * DMODEL / 8;     // 1048576
        const int wn8 = DMODEL * DMODEL / 8;           // 131072
        cast_kernel<<<(xn8 + 255) / 256, 256, 0, stream>>>(x, Xb, xn8);
        cast_kernel<<<(wn8 + 255) / 256, 256, 0, stream>>>(Wq, Wb, wn8);
        cast_kernel<<<(wn8 + 255) / 256, 256, 0, stream>>>(Wk, Wb + (size_t)DMODEL * DMODEL, wn8);
        cast_kernel<<<(wn8 + 255) / 256, 256, 0, stream>>>(Wv, Wb + (size_t)2 * DMODEL * DMODEL, wn8);
        gemm_qkv_bf16<<<dim3(64, 8, 3), 256, 0, stream>>>(Xb, Wb, qb, kb, vb);
    } else {
        gemm_qkv_f32<<<dim3(64, 8, 3), 256, 0, stream>>>(x, Wq, Wk, Wv, qb, kb, vb);
    }
    attn_kernel<<<dim3(NPTS, BATCH), 256, 0, stream>>>(qb, kb, vb, nbr, out);
    metric_kernel<<<(BATCH * NPTS * HDIM + 255) / 256, 256, 0, stream>>>(kb, out + (size_t)BATCH * NPTS * DMODEL);
}

// Round 5
// 217.553 us; speedup vs baseline: 2.0126x; 1.0480x over previous
//
#include <hip/hip_runtime.h>
#include <hip/hip_bf16.h>
#include <stdint.h>

// Problem constants
#define BATCH 2
#define NPTS 4096
#define DMODEL 1024
#define NHEAD 16
#define HDIM 64
#define KNN 16
#define MASKN 131072   // 32*64*64
#define EBLK 128       // extraction blocks (1024 mask elems each)

typedef __attribute__((ext_vector_type(8))) short bf16x8;
typedef __attribute__((ext_vector_type(4))) float f32x4;

__device__ __forceinline__ float b2f(unsigned short u) {
    union { unsigned int i; float f; } c; c.i = ((unsigned int)u) << 16; return c.f;
}
__device__ __forceinline__ unsigned short f2b(float f) {
    unsigned int x = __float_as_uint(f);
    unsigned int r = (x + 0x7fffu + ((x >> 16) & 1u)) >> 16;
    return (unsigned short)r;
}
__device__ __forceinline__ unsigned int pack2f(float a, float b) {
    return (unsigned int)f2b(a) | ((unsigned int)f2b(b) << 16);
}
// async global->LDS, 16B per lane. lptr must be wave-uniform; HW writes lptr + lane*16.
__device__ __forceinline__ void gload16(const unsigned short* g, unsigned short* l) {
    __builtin_amdgcn_global_load_lds((const __attribute__((address_space(1))) void*)g,
                                     (__attribute__((address_space(3))) void*)l, 16, 0, 0);
}

// ---------------------------------------------------------------------------
// 1) Parallel active-index extraction (3 tiny kernels, no atomics, OOB-safe)
// ---------------------------------------------------------------------------
__global__ __launch_bounds__(256) void count8_kernel(const unsigned char* __restrict__ m8,
                                                     int* __restrict__ cnt8) {
    __shared__ int red[256];
    const int b = blockIdx.x, t = threadIdx.x;
    const uchar4 v = ((const uchar4*)m8)[b * 256 + t];
    red[t] = (v.x != 0) + (v.y != 0) + (v.z != 0) + (v.w != 0);
    __syncthreads();
    for (int off = 128; off >= 1; off >>= 1) {
        if (t < off) red[t] += red[t + off];
        __syncthreads();
    }
    if (t == 0) cnt8[b] = red[0];
}

__global__ __launch_bounds__(256) void count32_kernel(const unsigned char* __restrict__ m8,
                                                      const int* __restrict__ cnt8,
                                                      int* __restrict__ cnt32) {
    __shared__ int red[256];
    const int b = blockIdx.x, t = threadIdx.x;
    red[t] = (t < EBLK) ? cnt8[t] : 0;
    __syncthreads();
    for (int off = 128; off >= 1; off >>= 1) {
        if (t < off) red[t] += red[t + off];
        __syncthreads();
    }
    if (red[0] == NPTS) return;     // mask is byte-bool; int view would be OOB
    __syncthreads();
    const int4 v = ((const int4*)m8)[b * 256 + t];
    red[t] = (v.x != 0) + (v.y != 0) + (v.z != 0) + (v.w != 0);
    __syncthreads();
    for (int off = 128; off >= 1; off >>= 1) {
        if (t < off) red[t] += red[t + off];
        __syncthreads();
    }
    if (t == 0) cnt32[b] = red[0];
}

__global__ __launch_bounds__(256) void extract_kernel(const unsigned char* __restrict__ m8,
                                                      const int* __restrict__ cnt8,
                                                      const int* __restrict__ cnt32,
                                                      int* __restrict__ act) {
    __shared__ int sblk[EBLK];
    __shared__ int sthr[256];
    const int b = blockIdx.x, t = threadIdx.x;
    if (t < EBLK) sblk[t] = cnt8[t];
    __syncthreads();
    for (int off = 1; off < EBLK; off <<= 1) {
        int v = (t < EBLK && t >= off) ? sblk[t - off] : 0;
        __syncthreads();
        if (t < EBLK) sblk[t] += v;
        __syncthreads();
    }
    const bool bytes = (sblk[EBLK - 1] == NPTS);   // grid-uniform
    if (!bytes) {
        __syncthreads();
        if (t < EBLK) sblk[t] = cnt32[t];
        __syncthreads();
        for (int off = 1; off < EBLK; off <<= 1) {
            int v = (t < EBLK && t >= off) ? sblk[t - off] : 0;
            __syncthreads();
            if (t < EBLK) sblk[t] += v;
            __syncthreads();
        }
    }
    const int blkoff = (b == 0) ? 0 : sblk[b - 1];
    const int gbase = b * 1024 + t * 4;
    int f0, f1, f2, f3;
    if (bytes) {
        const uchar4 v = ((const uchar4*)m8)[b * 256 + t];
        f0 = v.x != 0; f1 = v.y != 0; f2 = v.z != 0; f3 = v.w != 0;
    } else {
        const int4 v = ((const int4*)m8)[b * 256 + t];
        f0 = v.x != 0; f1 = v.y != 0; f2 = v.z != 0; f3 = v.w != 0;
    }
    const int c = f0 + f1 + f2 + f3;
    sthr[t] = c;
    __syncthreads();
    for (int off = 1; off < 256; off <<= 1) {
        int v = (t >= off) ? sthr[t - off] : 0;
        __syncthreads();
        sthr[t] += v;
        __syncthreads();
    }
    int pos = blkoff + sthr[t] - c;
    if (f0) act[pos++] = gbase;
    if (f1) act[pos++] = gbase + 1;
    if (f2) act[pos++] = gbase + 2;
    if (f3) act[pos++] = gbase + 3;
}

// ---------------------------------------------------------------------------
// 2) kNN: 16 threads/query, 16 queries/block -> 256 blocks.
// ---------------------------------------------------------------------------
__global__ __launch_bounds__(256) void knn_kernel(const int* __restrict__ act,
                                                  int* __restrict__ nbr) {
    __shared__ int act_s[NPTS];
    const int t = threadIdx.x;
    for (int i = t; i < NPTS; i += 256) act_s[i] = act[i];
    __syncthreads();
    const int q = blockIdx.x * 16 + (t >> 4);
    const int sub = t & 15;
    const int aq = act_s[q];
    const int qz = aq >> 12, qy = (aq >> 6) & 63, qx = aq & 63;
    int best[17];
    #pragma unroll
    for (int i = 0; i < 17; ++i) best[i] = 0x7FFFFFFF;
    for (int j = sub; j < NPTS; j += 16) {
        const int aj = act_s[j];
        const int dz = (aj >> 12) - qz;
        const int dy = ((aj >> 6) & 63) - qy;
        const int dx = (aj & 63) - qx;
        const int d2 = dz * dz + dy * dy + dx * dx;
        int p = (d2 << 12) | j;
        if (p < best[16]) {
            #pragma unroll
            for (int u = 0; u < 17; ++u) {
                const bool lt = p < best[u];
                const int tmp = best[u];
                best[u] = lt ? p : best[u];
                p = lt ? tmp : p;
            }
        }
    }
    int head = best[0];
    int keep = 0;
    #pragma unroll
    for (int r = 0; r < KNN + 1; ++r) {
        int m = head;
        #pragma unroll
        for (int off = 8; off >= 1; off >>= 1) m = min(m, __shfl_xor(m, off, 16));
        if (sub == r - 1) keep = m;
        const bool win = (head == m);
        #pragma unroll
        for (int u = 0; u < 16; ++u) if (win) best[u] = best[u + 1];
        if (win) best[16] = 0x7FFFFFFF;
        head = best[0];
    }
    nbr[q * KNN + sub] = keep & 4095;
}

// ---------------------------------------------------------------------------
// 3a) f32 -> bf16 cast (memory-bound, 8 elems/thread)
// ---------------------------------------------------------------------------
__global__ __launch_bounds__(256) void cast_kernel(const float* __restrict__ src,
                                                   unsigned short* __restrict__ dst, int n8) {
    const int i = blockIdx.x * 256 + threadIdx.x;
    if (i >= n8) return;
    const float4 a = ((const float4*)src)[2 * i];
    const float4 b = ((const float4*)src)[2 * i + 1];
    uint4 w;
    w.x = pack2f(a.x, a.y); w.y = pack2f(a.z, a.w);
    w.z = pack2f(b.x, b.y); w.w = pack2f(b.z, b.w);
    ((uint4*)dst)[i] = w;
}

// ---------------------------------------------------------------------------
// 3b) QKV GEMM, pipelined: BK=32 double-buffer (32KB LDS), counted vmcnt
//     (never drains in-loop), raw s_barriers, T2 chunk-swizzle both sides,
//     setprio around the MFMA cluster. C[m][n] = sum_k Xb[m][k]*W[n][k].
// ---------------------------------------------------------------------------
__global__ __launch_bounds__(256) void gemm_qkv_bf16(
    const unsigned short* __restrict__ Xb,
    const unsigned short* __restrict__ Wb,   // 3 contiguous 1024x1024 bf16
    unsigned short* __restrict__ O0, unsigned short* __restrict__ O1, unsigned short* __restrict__ O2)
{
    const int K = DMODEL, N = DMODEL;
    const unsigned short* W = Wb + (size_t)blockIdx.z * DMODEL * DMODEL;
    unsigned short* C = (blockIdx.z == 0) ? O0 : (blockIdx.z == 1) ? O1 : O2;
    __shared__ unsigned short As[2][128 * 32];   // [buf][row*32 + chunk*8]
    __shared__ unsigned short Bs[2][128 * 32];
    const int tid = threadIdx.x;
    const int rowBase = blockIdx.x * 128;
    const int colBase = blockIdx.y * 128;
    const int lane = tid & 63, w = tid >> 6;
    const int wr = w >> 1, wc = w & 1;
    const int lr = lane & 15, kg = lane >> 4;

    f32x4 acc[4][4];
    const f32x4 zero = {0.f, 0.f, 0.f, 0.f};
    #pragma unroll
    for (int i = 0; i < 4; ++i)
        #pragma unroll
        for (int j = 0; j < 4; ++j) acc[i][j] = zero;

    // ---- staging addresses (swizzled source, linear LDS dest) ----
    // thread t covers (row = round*64 + t>>2, chunk = t&3); source chunk
    // pre-swizzled: xch = (t&3) ^ ((t>>2)&3). Row+64 keeps (&3) -> same xch.
    const int srow4 = tid >> 2;
    const int xch = (tid & 3) ^ (srow4 & 3);
    const unsigned short* agp = &Xb[(size_t)(rowBase + srow4) * K + xch * 8];
    const unsigned short* bgp = &W[(size_t)(colBase + srow4) * K + xch * 8];
    // wave-uniform LDS bases (ushort units): round r at r*2048, wave at w*512
    unsigned short* a0[2] = { &As[0][w * 512], &As[1][w * 512] };
    unsigned short* a1[2] = { &As[0][2048 + w * 512], &As[1][2048 + w * 512] };
    unsigned short* b0[2] = { &Bs[0][w * 512], &Bs[1][w * 512] };
    unsigned short* b1[2] = { &Bs[0][2048 + w * 512], &Bs[1][2048 + w * 512] };

    #define STAGE(kt, bf) do { \
        gload16(agp + (kt) * 32,           a0[bf]); \
        gload16(agp + 64 * K + (kt) * 32,  a1[bf]); \
        gload16(bgp + (kt) * 32,           b0[bf]); \
        gload16(bgp + 64 * K + (kt) * 32,  b1[bf]); \
    } while (0)

    // read offsets (swizzled): physical chunk = kg ^ (r&3), r&3 == lr&3
    const int rchunk = (kg ^ (lr & 3)) * 8;

    #define COMPUTE(bf) do { \
        bf16x8 af[4], bfr[4]; \
        _Pragma("unroll") \
        for (int mi = 0; mi < 4; ++mi) \
            af[mi] = *(const bf16x8*)&As[bf][(wr * 64 + mi * 16 + lr) * 32 + rchunk]; \
        _Pragma("unroll") \
        for (int ni = 0; ni < 4; ++ni) \
            bfr[ni] = *(const bf16x8*)&Bs[bf][(wc * 64 + ni * 16 + lr) * 32 + rchunk]; \
        __builtin_amdgcn_s_setprio(1); \
        _Pragma("unroll") \
        for (int mi = 0; mi < 4; ++mi) \
            _Pragma("unroll") \
            for (int ni = 0; ni < 4; ++ni) \
                acc[mi][ni] = __builtin_amdgcn_mfma_f32_16x16x32_bf16(af[mi], bfr[ni], acc[mi][ni], 0, 0, 0); \
        __builtin_amdgcn_s_setprio(0); \
    } while (0)

    // prologue: tiles 0,1 in flight (8 loads/thread outstanding)
    STAGE(0, 0);
    STAGE(1, 1);
    // main loop: tiles 0..29 (each stages kt+2 into its own buffer after use)
    for (int kt = 0; kt < 30; ++kt) {
        const int bf = kt & 1;
        asm volatile("s_waitcnt vmcnt(4)" ::: "memory");  // this buffer's loads done
        __builtin_amdgcn_s_barrier();                     // published block-wide
        COMPUTE(bf);
        __builtin_amdgcn_s_barrier();                     // all reads of buf done
        STAGE(kt + 2, bf);                                // overwrite safely, stay in flight
    }
    // peeled tails: kt=30 (4 loads still in flight), kt=31 (drain)
    asm volatile("s_waitcnt vmcnt(4)" ::: "memory");
    __builtin_amdgcn_s_barrier();
    COMPUTE(0);
    __builtin_amdgcn_s_barrier();
    asm volatile("s_waitcnt vmcnt(0)" ::: "memory");
    __builtin_amdgcn_s_barrier();
    COMPUTE(1);
    #undef STAGE
    #undef COMPUTE

    // Epilogue: D row = (lane>>4)*4 + j, col = lane&15
    #pragma unroll
    for (int mi = 0; mi < 4; ++mi)
        #pragma unroll
        for (int ni = 0; ni < 4; ++ni) {
            const int row0 = rowBase + wr * 64 + mi * 16 + kg * 4;
            const int col = colBase + wc * 64 + ni * 16 + lr;
            #pragma unroll
            for (int j = 0; j < 4; ++j)
                C[(size_t)(row0 + j) * N + col] = f2b(acc[mi][ni][j]);
        }
}

// ---------------------------------------------------------------------------
// 3c) FALLBACK f32-input GEMM (used only if ws too small for bf16 copies)
// ---------------------------------------------------------------------------
__device__ __forceinline__ void stage16(unsigned short* dst, const float* src) {
    const float4 a = ((const float4*)src)[0];
    const float4 b = ((const float4*)src)[1];
    const float4 c = ((const float4*)src)[2];
    const float4 d = ((const float4*)src)[3];
    uint4 w0, w1;
    w0.x = pack2f(a.x, a.y); w0.y = pack2f(a.z, a.w);
    w0.z = pack2f(b.x, b.y); w0.w = pack2f(b.z, b.w);
    w1.x = pack2f(c.x, c.y); w1.y = pack2f(c.z, c.w);
    w1.z = pack2f(d.x, d.y); w1.w = pack2f(d.z, d.w);
    ((uint4*)dst)[0] = w0;
    ((uint4*)dst)[1] = w1;
}

__global__ __launch_bounds__(256) void gemm_qkv_f32(
    const float* __restrict__ X,
    const float* __restrict__ W0, const float* __restrict__ W1, const float* __restrict__ W2,
    unsigned short* __restrict__ O0, unsigned short* __restrict__ O1, unsigned short* __restrict__ O2)
{
    const int K = DMODEL, N = DMODEL;
    const float* W = (blockIdx.z == 0) ? W0 : (blockIdx.z == 1) ? W1 : W2;
    unsigned short* C = (blockIdx.z == 0) ? O0 : (blockIdx.z == 1) ? O1 : O2;
    __shared__ unsigned short As[128 * 32];
    __shared__ unsigned short Bs[128 * 32];
    const int tid = threadIdx.x;
    const int rowBase = blockIdx.x * 128;
    const int colBase = blockIdx.y * 128;
    const int lane = tid & 63, w = tid >> 6;
    const int wr = w >> 1, wc = w & 1;
    const int lr = lane & 15, kg = lane >> 4;
    const int srow = tid >> 1;
    const int scol = (tid & 1) * 16;
    f32x4 acc[4][4];
    const f32x4 zero = {0.f, 0.f, 0.f, 0.f};
    #pragma unroll
    for (int i = 0; i < 4; ++i)
        #pragma unroll
        for (int j = 0; j < 4; ++j) acc[i][j] = zero;
    const float* Arow = &X[(size_t)(rowBase + srow) * K + scol];
    const float* Brow = &W[(size_t)(colBase + srow) * K + scol];
    unsigned short* Adst = &As[srow * 32 + scol];
    unsigned short* Bdst = &Bs[srow * 32 + scol];
    for (int kb = 0; kb < K; kb += 32) {
        __syncthreads();
        stage16(Adst, Arow + kb);
        stage16(Bdst, Brow + kb);
        __syncthreads();
        bf16x8 af[4], bfr[4];
        #pragma unroll
        for (int mi = 0; mi < 4; ++mi)
            af[mi] = *(const bf16x8*)&As[(wr * 64 + mi * 16 + lr) * 32 + kg * 8];
        #pragma unroll
        for (int ni = 0; ni < 4; ++ni)
            bfr[ni] = *(const bf16x8*)&Bs[(wc * 64 + ni * 16 + lr) * 32 + kg * 8];
        #pragma unroll
        for (int mi = 0; mi < 4; ++mi)
            #pragma unroll
            for (int ni = 0; ni < 4; ++ni)
                acc[mi][ni] = __builtin_amdgcn_mfma_f32_16x16x32_bf16(af[mi], bfr[ni], acc[mi][ni], 0, 0, 0);
    }
    #pragma unroll
    for (int mi = 0; mi < 4; ++mi)
        #pragma unroll
        for (int ni = 0; ni < 4; ++ni) {
            const int row0 = rowBase + wr * 64 + mi * 16 + kg * 4;
            const int col = colBase + wc * 64 + ni * 16 + lr;
            #pragma unroll
            for (int j = 0; j < 4; ++j)
                C[(size_t)(row0 + j) * N + col] = f2b(acc[mi][ni][j]);
        }
}

// ---------------------------------------------------------------------------
// 4) Attention: one block per (b,n).
// ---------------------------------------------------------------------------
__global__ __launch_bounds__(256) void attn_kernel(
    const unsigned short* __restrict__ Q, const unsigned short* __restrict__ Kb,
    const unsigned short* __restrict__ Vb, const int* __restrict__ nbr,
    float* __restrict__ out)
{
    const int n = blockIdx.x;
    const int b = blockIdx.y;
    __shared__ unsigned short q_s[DMODEL];
    __shared__ unsigned short k_s[KNN][1028];
    __shared__ unsigned short v_s[KNN][DMODEL];
    __shared__ float a_s[NHEAD][KNN];
    __shared__ int nb_s[KNN];
    const int tid = threadIdx.x;
    if (tid < KNN) nb_s[tid] = nbr[n * KNN + tid];
    *(int2*)&q_s[tid * 4] = *(const int2*)&Q[((size_t)b * NPTS + n) * DMODEL + tid * 4];
    __syncthreads();
    #pragma unroll
    for (int kk = 0; kk < KNN; ++kk) {
        const int j = nb_s[kk];
        const size_t base = ((size_t)b * NPTS + j) * DMODEL;
        *(int2*)&k_s[kk][tid * 4] = *(const int2*)&Kb[base + tid * 4];
        *(int2*)&v_s[kk][tid * 4] = *(const int2*)&Vb[base + tid * 4];
    }
    __syncthreads();
    const int h = tid >> 4, kk = tid & 15;
    const unsigned short* qp = &q_s[h * HDIM];
    const unsigned short* kp = &k_s[kk][h * HDIM];
    float s = 0.f;
    #pragma unroll
    for (int d = 0; d < HDIM; ++d) s += b2f(qp[d]) * b2f(kp[d]);
    s *= 0.125f;
    float m = s;
    #pragma unroll
    for (int off = 8; off >= 1; off >>= 1) m = fmaxf(m, __shfl_xor(m, off, 16));
    const float e = __expf(s - m);
    float sum = e;
    #pragma unroll
    for (int off = 8; off >= 1; off >>= 1) sum += __shfl_xor(sum, off, 16);
    a_s[h][kk] = e / sum;
    __syncthreads();
    const size_t obase = ((size_t)b * NPTS + n) * DMODEL;
    #pragma unroll
    for (int r = 0; r < 4; ++r) {
        const int o = tid + 256 * r;
        const int h2 = o >> 6;
        float accv = 0.f;
        #pragma unroll
        for (int k2 = 0; k2 < KNN; ++k2) accv += a_s[h2][k2] * b2f(v_s[k2][o]);
        out[obase + o] = accv;
    }
}

// ---------------------------------------------------------------------------
// 5) metric = k.mean(axis=H)
// ---------------------------------------------------------------------------
__global__ __launch_bounds__(256) void metric_kernel(const unsigned short* __restrict__ Kb,
                                                     float* __restrict__ mout) {
    const int i = blockIdx.x * 256 + threadIdx.x;
    if (i >= BATCH * NPTS * HDIM) return;
    const int d = i & 63;
    const int bn = i >> 6;
    const unsigned short* kp = &Kb[(size_t)bn * DMODEL + d];
    float s = 0.f;
    #pragma unroll
    for (int hh = 0; hh < NHEAD; ++hh) s += b2f(kp[hh * HDIM]);
    mout[i] = s * 0.0625f;
}

// ---------------------------------------------------------------------------
extern "C" void kernel_launch(void* const* d_in, const int* in_sizes, int n_in,
                              void* d_out, int out_size, void* d_ws, size_t ws_size,
                              hipStream_t stream) {
    const float* x = (const float*)d_in[0];
    const unsigned char* mask = (const unsigned char*)d_in[1];
    const float* Wq = (const float*)d_in[2];
    const float* Wk = (const float*)d_in[3];
    const float* Wv = (const float*)d_in[4];
    float* out = (float*)d_out;
    char* ws = (char*)d_ws;

    const size_t QKV_BYTES = (size_t)BATCH * NPTS * DMODEL * 2;   // 16.78 MB each
    const size_t XB_BYTES  = (size_t)BATCH * NPTS * DMODEL * 2;   // 16.78 MB
    const size_t WB_BYTES  = (size_t)3 * DMODEL * DMODEL * 2;     // 6.29 MB
    unsigned short* qb = (unsigned short*)(ws);
    unsigned short* kb = (unsigned short*)(ws + QKV_BYTES);
    unsigned short* vb = (unsigned short*)(ws + 2 * QKV_BYTES);
    const size_t SMALL_BYTES = (size_t)NPTS * sizeof(int) * (1 + KNN) + 2 * EBLK * sizeof(int);
    const size_t need_base = 3 * QKV_BYTES + SMALL_BYTES;
    const size_t need_full = need_base + XB_BYTES + WB_BYTES;
    const bool full = (ws_size >= need_full);
    char* tail = ws + 3 * QKV_BYTES;
    unsigned short* Xb = (unsigned short*)tail;
    unsigned short* Wb = (unsigned short*)(tail + XB_BYTES);
    char* small = full ? (tail + XB_BYTES + WB_BYTES) : tail;
    int* act  = (int*)small;
    int* nbr  = (int*)(small + NPTS * sizeof(int));
    int* cnt8 = (int*)(small + NPTS * sizeof(int) * (1 + KNN));
    int* cnt32 = cnt8 + EBLK;
    if (ws_size < need_base) return;

    count8_kernel<<<EBLK, 256, 0, stream>>>(mask, cnt8);
    count32_kernel<<<EBLK, 256, 0, stream>>>(mask, cnt8, cnt32);
    extract_kernel<<<EBLK, 256, 0, stream>>>(mask, cnt8, cnt32, act);
    knn_kernel<<<256, 256, 0, stream>>>(act, nbr);
    if (full) {
        const int xn8 = BATCH * NPTS * DMODEL / 8;     // 1048576
        const int wn8 = DMODEL * DMODEL / 8;           // 131072
        cast_kernel<<<(xn8 + 255) / 256, 256, 0, stream>>>(x, Xb, xn8);
        cast_kernel<<<(wn8 + 255) / 256, 256, 0, stream>>>(Wq, Wb, wn8);
        cast_kernel<<<(wn8 + 255) / 256, 256, 0, stream>>>(Wk, Wb + (size_t)DMODEL * DMODEL, wn8);
        cast_kernel<<<(wn8 + 255) / 256, 256, 0, stream>>>(Wv, Wb + (size_t)2 * DMODEL * DMODEL, wn8);
        gemm_qkv_bf16<<<dim3(64, 8, 3), 256, 0, stream>>>(Xb, Wb, qb, kb, vb);
    } else {
        gemm_qkv_f32<<<dim3(64, 8, 3), 256, 0, stream>>>(x, Wq, Wk, Wv, qb, kb, vb);
    }
    attn_kernel<<<dim3(NPTS, BATCH), 256, 0, stream>>>(qb, kb, vb, nbr, out);
    metric_kernel<<<(BATCH * NPTS * HDIM + 255) / 256, 256, 0, stream>>>(kb, out + (size_t)BATCH * NPTS * DMODEL);
}